// Round 16
// baseline (740.845 us; speedup 1.0000x reference)
//
#include <hip/hip_runtime.h>
#include <hip/hip_bf16.h>

// MHRetention (B=4, L=4096, EMB=2048, H=16, hd=128), fp32 in/out, bf16 MFMA compute.
// Round-16: byte-identical revert to the verified round-14 kernel (740 us).
// Round-15's persistent-seam restructure broke replay determinism (race; suspect
// scratch-spill ops corrupting hand-counted vmcnt) and was abandoned.
// gemm256P: paired projections (Q+U, K+V) as N=4096 GEMMs, verified 8-phase
// counted-vmcnt K-loop, scatter epilogue. gemmO: fused SRMS-norm*U epilogue.

typedef unsigned int u32;
typedef unsigned short u16;
typedef __bf16 bf16x8 __attribute__((ext_vector_type(8)));
typedef float f32x4 __attribute__((ext_vector_type(4)));

__device__ __forceinline__ u16 f2bf(float f) {
  u32 u = __float_as_uint(f);
  u = (u + 0x7fffu + ((u >> 16) & 1u)) >> 16;
  return (u16)u;
}
__device__ __forceinline__ float bf2f(u16 s) { return __uint_as_float(((u32)s) << 16); }

__device__ __forceinline__ void gl_lds16(const void* g, void* l) {
  __builtin_amdgcn_global_load_lds((const __attribute__((address_space(1))) void*)g,
                                   (__attribute__((address_space(3))) void*)l, 16, 0, 0);
}

__device__ __forceinline__ void bar() {
  asm volatile("" ::: "memory");
  __builtin_amdgcn_s_barrier();
  asm volatile("" ::: "memory");
}

#define INV_SCALE 0.08838834764831845f  // 1/sqrt(128)

// ---------------- fp32 -> bf16 conversion ----------------
__global__ __launch_bounds__(256) void cvt_f32_bf16(const float4* __restrict__ in,
                                                    u16* __restrict__ out, int n4) {
  int i = blockIdx.x * 256 + threadIdx.x;
  int stride = gridDim.x * 256;
  for (; i < n4; i += stride) {
    float4 v = in[i];
    u32 lo = (u32)f2bf(v.x) | ((u32)f2bf(v.y) << 16);
    u32 hi = (u32)f2bf(v.z) | ((u32)f2bf(v.w) << 16);
    ((uint2*)out)[i] = make_uint2(lo, hi);
  }
}

// two 2048x2048 fp32 weights -> one concatenated bf16 buffer [wA; wB]
__global__ __launch_bounds__(256) void cvt2_f32_bf16(const float4* __restrict__ a,
                                                     const float4* __restrict__ b,
                                                     u16* __restrict__ out) {
  int i = blockIdx.x * 256 + threadIdx.x;
  int stride = gridDim.x * 256;
  for (; i < 2097152; i += stride) {
    float4 v = (i < 1048576) ? a[i] : b[i - 1048576];
    u32 lo = (u32)f2bf(v.x) | ((u32)f2bf(v.y) << 16);
    u32 hi = (u32)f2bf(v.z) | ((u32)f2bf(v.w) << 16);
    ((uint2*)out)[i] = make_uint2(lo, hi);
  }
}

// ---- shared K-loop body (verified rounds 6..14) ----
#define GEMM_CORE_DECLS                                                                  \
  __shared__ __align__(16) char smem[131072];                                            \
  const int t = threadIdx.x;                                                             \
  const int u = t & 63;                                                                  \
  const int wid = t >> 6;                                                                \
  const int wm = wid >> 2;                                                               \
  const int wn = wid & 3;                                                                \
  const int srow = t >> 3;                                                               \
  const int scol = ((t & 7) ^ (srow & 7)) * 8;                                           \
  const int ard = wm * 16384;                                                            \
  const int brd = 32768 + (wn >> 1) * 16384;                                             \
  const int arow = (u & 15) * 128;                                                       \
  const int brow = ((wn & 1) * 64 + (u & 15)) * 128;                                     \
  const int cr0 = ((u >> 4) ^ (u & 7)) * 16;                                             \
  const int cr1 = ((4 + (u >> 4)) ^ (u & 7)) * 16;

#define STG(base, R, kb, reg)                                                            \
  {                                                                                      \
    gl_lds16((base) + (size_t)((R) + srow) * 2048 + (kb) + scol, smem + (reg) + t * 16); \
    gl_lds16((base) + (size_t)((R) + 64 + srow) * 2048 + (kb) + scol,                    \
             smem + (reg) + 8192 + t * 16);                                              \
  }

#define LDA(buf, mi, cr) (*(const bf16x8*)(smem + (buf) + ard + arow + (mi) * 2048 + (cr)))
#define LDB(buf, ni, cr) (*(const bf16x8*)(smem + (buf) + brd + brow + (ni) * 2048 + (cr)))
#define MFMA(d, a_, b_) d = __builtin_amdgcn_mfma_f32_16x16x32_bf16(a_, b_, d, 0, 0, 0)
#define QUAD(MB, NB, B_0, B_1, B_2, B_3)                                    \
  MFMA(acc[MB + 0][NB + 0], a00, B_0); MFMA(acc[MB + 0][NB + 1], a00, B_2); \
  MFMA(acc[MB + 1][NB + 0], a10, B_0); MFMA(acc[MB + 1][NB + 1], a10, B_2); \
  MFMA(acc[MB + 2][NB + 0], a20, B_0); MFMA(acc[MB + 2][NB + 1], a20, B_2); \
  MFMA(acc[MB + 3][NB + 0], a30, B_0); MFMA(acc[MB + 3][NB + 1], a30, B_2); \
  MFMA(acc[MB + 0][NB + 0], a01, B_1); MFMA(acc[MB + 0][NB + 1], a01, B_3); \
  MFMA(acc[MB + 1][NB + 0], a11, B_1); MFMA(acc[MB + 1][NB + 1], a11, B_3); \
  MFMA(acc[MB + 2][NB + 0], a21, B_1); MFMA(acc[MB + 2][NB + 1], a21, B_3); \
  MFMA(acc[MB + 3][NB + 0], a31, B_1); MFMA(acc[MB + 3][NB + 1], a31, B_3);

#define GEMM_KLOOP(Asrc, Bsrc)                                                           \
  f32x4 acc[8][4];                                                                       \
  _Pragma("unroll") for (int i = 0; i < 8; ++i)                                          \
      _Pragma("unroll") for (int j = 0; j < 4; ++j) acc[i][j] = (f32x4){0.f, 0.f, 0.f, 0.f}; \
  bf16x8 a00, a01, a10, a11, a20, a21, a30, a31;                                         \
  bf16x8 b00, b01, b10, b11, b20, b21, b30, b31;                                         \
  STG(Bsrc, 0, 0, 32768) STG(Bsrc, 128, 0, 49152)                                        \
  STG(Asrc, 0, 0, 0) STG(Asrc, 128, 0, 16384)                                            \
  STG(Bsrc, 0, 64, 65536 + 32768) STG(Bsrc, 128, 64, 65536 + 49152)                      \
  asm volatile("s_waitcnt vmcnt(4)" ::: "memory");                                       \
  bar();                                                                                 \
  for (int i = 0; i < 16; ++i) {                                                         \
    const int kA1 = (2 * i + 1) * 64;                                                    \
    const int kT2 = (2 * i + 2) * 64;                                                    \
    const int kB3 = (2 * i + 3) * 64;                                                    \
    a00 = LDA(0, 0, cr0); a01 = LDA(0, 0, cr1); a10 = LDA(0, 1, cr0); a11 = LDA(0, 1, cr1); \
    a20 = LDA(0, 2, cr0); a21 = LDA(0, 2, cr1); a30 = LDA(0, 3, cr0); a31 = LDA(0, 3, cr1); \
    b00 = LDB(0, 0, cr0); b01 = LDB(0, 0, cr1); b10 = LDB(0, 1, cr0); b11 = LDB(0, 1, cr1); \
    STG(Asrc, 0, kA1, 65536 + 0)                                                         \
    bar();                                                                               \
    __builtin_amdgcn_s_setprio(1); QUAD(0, 0, b00, b01, b10, b11) __builtin_amdgcn_s_setprio(0); \
    bar();                                                                               \
    b20 = LDB(0, 2, cr0); b21 = LDB(0, 2, cr1); b30 = LDB(0, 3, cr0); b31 = LDB(0, 3, cr1); \
    STG(Asrc, 128, kA1, 65536 + 16384)                                                   \
    bar();                                                                               \
    __builtin_amdgcn_s_setprio(1); QUAD(0, 2, b20, b21, b30, b31) __builtin_amdgcn_s_setprio(0); \
    bar();                                                                               \
    a00 = LDA(0, 4, cr0); a01 = LDA(0, 4, cr1); a10 = LDA(0, 5, cr0); a11 = LDA(0, 5, cr1); \
    a20 = LDA(0, 6, cr0); a21 = LDA(0, 6, cr1); a30 = LDA(0, 7, cr0); a31 = LDA(0, 7, cr1); \
    if (i < 15) STG(Bsrc, 0, kT2, 32768)                                                 \
    bar();                                                                               \
    __builtin_amdgcn_s_setprio(1); QUAD(4, 0, b00, b01, b10, b11) __builtin_amdgcn_s_setprio(0); \
    bar();                                                                               \
    if (i < 15) STG(Bsrc, 128, kT2, 49152)                                               \
    bar();                                                                               \
    __builtin_amdgcn_s_setprio(1); QUAD(4, 2, b20, b21, b30, b31) __builtin_amdgcn_s_setprio(0); \
    if (i == 15) { asm volatile("s_waitcnt vmcnt(0)" ::: "memory"); }                    \
    else         { asm volatile("s_waitcnt vmcnt(4)" ::: "memory"); }                    \
    bar();                                                                               \
    a00 = LDA(65536, 0, cr0); a01 = LDA(65536, 0, cr1); a10 = LDA(65536, 1, cr0); a11 = LDA(65536, 1, cr1); \
    a20 = LDA(65536, 2, cr0); a21 = LDA(65536, 2, cr1); a30 = LDA(65536, 3, cr0); a31 = LDA(65536, 3, cr1); \
    b00 = LDB(65536, 0, cr0); b01 = LDB(65536, 0, cr1); b10 = LDB(65536, 1, cr0); b11 = LDB(65536, 1, cr1); \
    if (i < 15) STG(Asrc, 0, kT2, 0)                                                     \
    bar();                                                                               \
    __builtin_amdgcn_s_setprio(1); QUAD(0, 0, b00, b01, b10, b11) __builtin_amdgcn_s_setprio(0); \
    bar();                                                                               \
    b20 = LDB(65536, 2, cr0); b21 = LDB(65536, 2, cr1); b30 = LDB(65536, 3, cr0); b31 = LDB(65536, 3, cr1); \
    if (i < 15) STG(Asrc, 128, kT2, 16384)                                               \
    bar();                                                                               \
    __builtin_amdgcn_s_setprio(1); QUAD(0, 2, b20, b21, b30, b31) __builtin_amdgcn_s_setprio(0); \
    bar();                                                                               \
    a00 = LDA(65536, 4, cr0); a01 = LDA(65536, 4, cr1); a10 = LDA(65536, 5, cr0); a11 = LDA(65536, 5, cr1); \
    a20 = LDA(65536, 6, cr0); a21 = LDA(65536, 6, cr1); a30 = LDA(65536, 7, cr0); a31 = LDA(65536, 7, cr1); \
    if (i < 15) STG(Bsrc, 0, kB3, 65536 + 32768)                                         \
    bar();                                                                               \
    __builtin_amdgcn_s_setprio(1); QUAD(4, 0, b00, b01, b10, b11) __builtin_amdgcn_s_setprio(0); \
    bar();                                                                               \
    if (i < 15) STG(Bsrc, 128, kB3, 65536 + 49152)                                       \
    bar();                                                                               \
    __builtin_amdgcn_s_setprio(1); QUAD(4, 2, b20, b21, b30, b31) __builtin_amdgcn_s_setprio(0); \
    asm volatile("s_waitcnt vmcnt(4)" ::: "memory");                                     \
    bar();                                                                               \
  }

// ===== paired projection GEMM: A[16384][2048] x W2[4096][2048]^T =====
// PAIR 0: region0 -> Qb (relu/scale), region1 -> Ub (silu)
// PAIR 1: region0 -> KT (relu/scale, per-head transpose), region1 -> VT (transpose)
template <int PAIR>
__global__ __launch_bounds__(512, 2) void gemm256P(const u16* __restrict__ Ab,
                                                   const u16* __restrict__ Bb,
                                                   u16* __restrict__ C0,
                                                   u16* __restrict__ C1) {
  GEMM_CORE_DECLS
  const int wgid = blockIdx.x;                  // 1024 blocks
  const int swz = (wgid & 7) * 128 + (wgid >> 3);
  const int mt = swz >> 4;                      // 0..63
  const int nt = swz & 15;                      // 0..15
  const u16* Asrc = Ab + (size_t)mt * 256 * 2048;
  const u16* Bsrc = Bb + (size_t)nt * 256 * 2048;

  GEMM_KLOOP(Asrc, Bsrc)

  const int mbase = mt * 256 + wm * 128;
  const int nbase = nt * 256 + wn * 64;         // 0..4095
  const int reg = nt >> 3;                      // block-uniform region
  u16* Cr = reg ? C1 : C0;
#pragma unroll
  for (int mi = 0; mi < 8; ++mi)
#pragma unroll
    for (int ni = 0; ni < 4; ++ni)
#pragma unroll
      for (int jj = 0; jj < 4; ++jj) {
        float v = acc[mi][ni][jj];
        int m = mbase + mi * 16 + ((u >> 4) << 2) + jj;
        int n = (nbase + ni * 16 + (u & 15)) & 2047;  // col within region
        if constexpr (PAIR == 0) {
          float o = (reg == 0) ? fmaxf(v, 0.f) * INV_SCALE
                               : v * (1.f / (1.f + __expf(-v)));
          Cr[(size_t)m * 2048 + n] = f2bf(o);
        } else {
          float q = (reg == 0) ? fmaxf(v, 0.f) * INV_SCALE : v;
          int bh = ((m >> 12) << 4) | (n >> 7);
          Cr[(size_t)bh * 524288 + (size_t)(n & 127) * 4096 + (m & 4095)] = f2bf(q);
        }
      }
}

// ===== final GEMM: Ob[16384][2048] x wo[2048][2048]^T -> fp32 d_out =====
__global__ __launch_bounds__(512, 2) void gemm256F(const u16* __restrict__ Ab,
                                                   const u16* __restrict__ Bb,
                                                   float* __restrict__ Cb) {
  GEMM_CORE_DECLS
  const int wgid = blockIdx.x;                  // 512 blocks
  const int swz = (wgid & 7) * 64 + (wgid >> 3);
  const int mt = swz >> 3;                      // 0..63
  const int nt = swz & 7;                       // 0..7
  const u16* Asrc = Ab + (size_t)mt * 256 * 2048;
  const u16* Bsrc = Bb + (size_t)nt * 256 * 2048;

  GEMM_KLOOP(Asrc, Bsrc)

  const int mbase = mt * 256 + wm * 128;
  const int nbase = nt * 256 + wn * 64;
#pragma unroll
  for (int mi = 0; mi < 8; ++mi)
#pragma unroll
    for (int ni = 0; ni < 4; ++ni)
#pragma unroll
      for (int jj = 0; jj < 4; ++jj) {
        int m = mbase + mi * 16 + ((u >> 4) << 2) + jj;
        int n = nbase + ni * 16 + (u & 15);
        Cb[(size_t)m * 2048 + n] = acc[mi][ni][jj];
      }
}

// ================= 128x128 KV-partial kernel (bf16 partials) =================
__global__ __launch_bounds__(256) void gemmKV(const u16* __restrict__ Ab,
                                              const u16* __restrict__ Bb,
                                              u16* __restrict__ Cb) {
  __shared__ __align__(16) char smem[16384];

  const int t = threadIdx.x;
  const int u = t & 63;
  const int wid = t >> 6;
  const int wr = wid >> 1, wc = wid & 1;

  const u16* Au = Ab + (size_t)blockIdx.y * 524288 + blockIdx.x * 1024;
  const u16* Bu = Bb + (size_t)blockIdx.y * 524288 + blockIdx.x * 1024;

  const int srow = t >> 2;
  const int scolb = (t & 3) * 16;

  f32x4 acc[4][4];
#pragma unroll
  for (int i = 0; i < 4; ++i)
#pragma unroll
    for (int j = 0; j < 4; ++j) acc[i][j] = (f32x4){0.f, 0.f, 0.f, 0.f};

  const int aoff = (wr * 64 + (u & 15)) * 64 + (u >> 4) * 16;
  const int boff = 8192 + (wc * 64 + (u & 15)) * 64 + (u >> 4) * 16;

  for (int k0 = 0; k0 < 1024; k0 += 32) {
    const char* ga = (const char*)Au + ((size_t)srow * 4096 + k0) * 2 + scolb;
    const char* gb = (const char*)Bu + ((size_t)srow * 4096 + k0) * 2 + scolb;
    gl_lds16(ga, smem + t * 16);
    gl_lds16(ga + (size_t)64 * 4096 * 2, smem + 4096 + t * 16);
    gl_lds16(gb, smem + 8192 + t * 16);
    gl_lds16(gb + (size_t)64 * 4096 * 2, smem + 12288 + t * 16);
    __syncthreads();

    bf16x8 af[4], bfr[4];
#pragma unroll
    for (int mi = 0; mi < 4; ++mi) af[mi] = *(const bf16x8*)(smem + aoff + mi * 1024);
#pragma unroll
    for (int ni = 0; ni < 4; ++ni) bfr[ni] = *(const bf16x8*)(smem + boff + ni * 1024);
#pragma unroll
    for (int mi = 0; mi < 4; ++mi)
#pragma unroll
      for (int ni = 0; ni < 4; ++ni)
        acc[mi][ni] = __builtin_amdgcn_mfma_f32_16x16x32_bf16(af[mi], bfr[ni], acc[mi][ni], 0, 0, 0);
    __syncthreads();
  }

#pragma unroll
  for (int mi = 0; mi < 4; ++mi)
#pragma unroll
    for (int ni = 0; ni < 4; ++ni)
#pragma unroll
      for (int j = 0; j < 4; ++j) {
        int ml = wr * 64 + mi * 16 + ((u >> 4) << 2) + j;
        int nl = wc * 64 + ni * 16 + (u & 15);
        Cb[((size_t)blockIdx.x * 64 + blockIdx.y) * 16384 + ml * 128 + nl] = f2bf(acc[mi][ni][j]);
      }
}

// ---------------- KV partial reduce: 4 bf16 chunks -> bf16 ----------------
__global__ __launch_bounds__(256) void kv_reduce(const u16* __restrict__ part,
                                                 u16* __restrict__ kvt) {
  int i = blockIdx.x * 256 + threadIdx.x;  // 1048576 elements
  float s = bf2f(part[i]) + bf2f(part[i + 1048576]) + bf2f(part[i + 2097152]) +
            bf2f(part[i + 3145728]);
  kvt[i] = f2bf(s);
}

// ======= gemmO: O = Q @ KVT^T per head, fused SRMS-norm * U epilogue =======
__global__ __launch_bounds__(256) void gemmO(const u16* __restrict__ Qb,
                                             const u16* __restrict__ KVT,
                                             const u16* __restrict__ Ub,
                                             u16* __restrict__ Ob) {
  __shared__ __align__(16) char smem[16384];
  __shared__ float ssb[2][128];

  const int t = threadIdx.x;
  const int u = t & 63;
  const int wid = t >> 6;
  const int wr = wid >> 1, wc = wid & 1;

  const int bh = blockIdx.y, b = bh >> 4, h = bh & 15;
  const int rowbase = b * 4096 + blockIdx.x * 128;
  const u16* Au = Qb + (size_t)rowbase * 2048 + h * 128;
  const u16* Bu = KVT + (size_t)bh * 16384;

  const int srow = t >> 2;
  const int scolb = (t & 3) * 16;

  f32x4 acc[4][4];
#pragma unroll
  for (int i = 0; i < 4; ++i)
#pragma unroll
    for (int j = 0; j < 4; ++j) acc[i][j] = (f32x4){0.f, 0.f, 0.f, 0.f};

  const int aoff = (wr * 64 + (u & 15)) * 64 + (u >> 4) * 16;
  const int boff = 8192 + (wc * 64 + (u & 15)) * 64 + (u >> 4) * 16;

  for (int k0 = 0; k0 < 128; k0 += 32) {
    const char* ga = (const char*)Au + ((size_t)srow * 2048 + k0) * 2 + scolb;
    const char* gb = (const char*)Bu + ((size_t)srow * 128 + k0) * 2 + scolb;
    gl_lds16(ga, smem + t * 16);
    gl_lds16(ga + (size_t)64 * 2048 * 2, smem + 4096 + t * 16);
    gl_lds16(gb, smem + 8192 + t * 16);
    gl_lds16(gb + (size_t)64 * 128 * 2, smem + 12288 + t * 16);
    __syncthreads();

    bf16x8 af[4], bfr[4];
#pragma unroll
    for (int mi = 0; mi < 4; ++mi) af[mi] = *(const bf16x8*)(smem + aoff + mi * 1024);
#pragma unroll
    for (int ni = 0; ni < 4; ++ni) bfr[ni] = *(const bf16x8*)(smem + boff + ni * 1024);
#pragma unroll
    for (int mi = 0; mi < 4; ++mi)
#pragma unroll
      for (int ni = 0; ni < 4; ++ni)
        acc[mi][ni] = __builtin_amdgcn_mfma_f32_16x16x32_bf16(af[mi], bfr[ni], acc[mi][ni], 0, 0, 0);
    __syncthreads();
  }

#pragma unroll
  for (int mi = 0; mi < 4; ++mi)
#pragma unroll
    for (int j = 0; j < 4; ++j) {
      float s = acc[mi][0][j] * acc[mi][0][j] + acc[mi][1][j] * acc[mi][1][j] +
                acc[mi][2][j] * acc[mi][2][j] + acc[mi][3][j] * acc[mi][3][j];
      s += __shfl_xor(s, 1); s += __shfl_xor(s, 2);
      s += __shfl_xor(s, 4); s += __shfl_xor(s, 8);
      if ((u & 15) == 0) ssb[wc][wr * 64 + mi * 16 + ((u >> 4) << 2) + j] = s;
    }
  __syncthreads();

#pragma unroll
  for (int mi = 0; mi < 4; ++mi)
#pragma unroll
    for (int j = 0; j < 4; ++j) {
      int ml = wr * 64 + mi * 16 + ((u >> 4) << 2) + j;
      float ss = ssb[0][ml] + ssb[1][ml];
      float inv = 1.0f / fmaxf(sqrtf(ss * (1.0f / 128.0f)), 1e-12f);
      size_t rb = (size_t)(rowbase + ml) * 2048 + h * 128;
#pragma unroll
      for (int ni = 0; ni < 4; ++ni) {
        int nl = wc * 64 + ni * 16 + (u & 15);
        float uval = bf2f(Ub[rb + nl]);
        Ob[rb + nl] = f2bf(acc[mi][ni][j] * inv * uval);
      }
    }
}

extern "C" void kernel_launch(void* const* d_in, const int* in_sizes, int n_in,
                              void* d_out, int out_size, void* d_ws, size_t ws_size,
                              hipStream_t stream) {
  (void)in_sizes; (void)n_in; (void)out_size; (void)ws_size;
  const float* x  = (const float*)d_in[0];
  const float* wq = (const float*)d_in[1];
  const float* wk = (const float*)d_in[2];
  const float* wv = (const float*)d_in[3];
  const float* wu = (const float*)d_in[4];
  const float* wo = (const float*)d_in[5];

  char* ws = (char*)d_ws;
  u16* wb2   = (u16*)(ws + 0);            // 16 MiB (two weights, reused per stage)
  u16* xb    = (u16*)(ws + 16777216);     // 64 MiB (reused as Ob later)
  u16* Qb    = (u16*)(ws + 83886080);     // 64 MiB
  u16* Ub    = (u16*)(ws + 150994944);    // 64 MiB
  u16* KVp   = (u16*)(ws + 218103808);    // 8 MiB: 4x64x128x128 bf16 partials
  u16* KVT   = (u16*)(ws + 226492416);    // 2 MiB (end: 228,589,568 B — proven bound)
  u16* Ob    = xb;
  u16* KT    = (u16*)d_out;               // d_out scratch (first 64 MiB)
  u16* VT    = (u16*)d_out + 33554432;    // d_out scratch (second 64 MiB)

  // x -> bf16
  cvt_f32_bf16<<<4096, 256, 0, stream>>>((const float4*)x, xb, 8388608);

  // Q + U merged (N=4096)
  cvt2_f32_bf16<<<4096, 256, 0, stream>>>((const float4*)wq, (const float4*)wu, wb2);
  gemm256P<0><<<1024, 512, 0, stream>>>(xb, wb2, Qb, Ub);

  // K + V merged (N=4096), per-head transposed into d_out
  cvt2_f32_bf16<<<4096, 256, 0, stream>>>((const float4*)wk, (const float4*)wv, wb2);
  gemm256P<1><<<1024, 512, 0, stream>>>(xb, wb2, KT, VT);

  // KVT[bh][e][d] = sum_l VT[e][l] * KT[d][l]  (bf16 partials -> fp32 reduce)
  gemmKV<<<dim3(4, 64), 256, 0, stream>>>(VT, KT, KVp);
  kv_reduce<<<4096, 256, 0, stream>>>(KVp, KVT);

  // O = Q @ KVT^T per head, fused SRMS*U -> Ob (= xb). KT/VT dead after this.
  gemmO<<<dim3(32, 64), 256, 0, stream>>>(Qb, KVT, Ub, Ob);

  // out = Ob @ wo^T (fp32, full overwrite of d_out)
  cvt_f32_bf16<<<4096, 256, 0, stream>>>((const float4*)wo, wb2, 1048576);
  gemm256F<<<512, 512, 0, stream>>>(Ob, wb2, (float*)d_out);
}